// Round 3
// baseline (732.378 us; speedup 1.0000x reference)
//
#include <hip/hip_runtime.h>
#include <hip/hip_bf16.h>
#include <stdint.h>

#define B_ 4
#define S_ 2048
#define H_ 1024
#define I_ 4096
#define E_ 8
#define CAP 640
#define NTOK (B_*S_)            // 8192
#define NBE  (B_*E_)            // 32

typedef _Float16 f16;
typedef f16 f16x8 __attribute__((ext_vector_type(8)));
typedef float f32x4 __attribute__((ext_vector_type(4)));

// workspace layout (bytes)
#define OFF_LOGITS 0u                          // 65536 f32
#define OFF_TOPKI  (256u*1024u)                // 20480 int
#define OFF_TOPKW  (OFF_TOPKI + 128u*1024u)    // 20480 f32
#define OFF_COUNTS (OFF_TOPKW + 128u*1024u)    // 8192 f32
#define OFF_SCAL   (OFF_COUNTS + 64u*1024u)    // 16 f32
#define OFF_XH     (1u<<20)                    // 8192*1024 f16   (16.8 MB)
#define OFF_WT     (18u<<20)                   // 8*4096*1024 f16 (67.1 MB) — w1t then w2t (reused)
#define OFF_MID    (86u<<20)                   // 20480*4096 f16  (167.8 MB) → high-water ~254 MB

__device__ __forceinline__ void gl_lds16(const void* g, void* l) {
    __builtin_amdgcn_global_load_lds(
        (const __attribute__((address_space(1))) uint32_t*)g,
        (__attribute__((address_space(3))) uint32_t*)l, 16, 0, 0);
}

// ---------------------------------------------------------------- router ----
// NOTE: summation order is frozen — top-k selection depends on exact fp32
// logit ordering near capacity boundaries. Do not restructure this reduce.
__global__ void k_router(const float* __restrict__ x, const float* __restrict__ rw,
                         float* __restrict__ logits, float* __restrict__ scal) {
    __shared__ float rwt[E_ * H_];
    __shared__ float part[4][9];
    int tid = threadIdx.x;
    for (int i = tid; i < E_ * H_; i += 256) {
        int h = i >> 3, e = i & 7;
        rwt[e * H_ + h] = rw[i];
    }
    __syncthreads();
    int w = tid >> 6, lane = tid & 63;
    int t = blockIdx.x * 4 + w;
    const float* xr = x + (size_t)t * H_;
    float acc[E_];
#pragma unroll
    for (int e = 0; e < E_; ++e) acc[e] = 0.f;
    for (int it = 0; it < H_ / 64; ++it) {
        int h = lane + it * 64;
        float xv = xr[h];
#pragma unroll
        for (int e = 0; e < E_; ++e) acc[e] += xv * rwt[e * H_ + h];
    }
#pragma unroll
    for (int off = 32; off > 0; off >>= 1)
#pragma unroll
        for (int e = 0; e < E_; ++e) acc[e] += __shfl_down(acc[e], off);
    if (lane == 0) {
        int b = t >> 11, s = t & 2047;
        float m = acc[0];
#pragma unroll
        for (int e = 1; e < E_; ++e) m = fmaxf(m, acc[e]);
        float z = 0.f, ps = 0.f;
        float p[E_];
#pragma unroll
        for (int e = 0; e < E_; ++e) {
            logits[(size_t)((b << 3) + e) * S_ + s] = acc[e];
            z += acc[e] * acc[e];
            p[e] = expf(acc[e] - m);
            ps += p[e];
        }
        part[w][0] = z;
#pragma unroll
        for (int e = 0; e < E_; ++e) part[w][1 + e] = p[e] / ps;
    }
    __syncthreads();
    if (tid < 9) {
        float v = part[0][tid] + part[1][tid] + part[2][tid] + part[3][tid];
        atomicAdd(&scal[tid], v);
    }
}

// ----------------------------------------------------------------- top-k ----
__global__ void __launch_bounds__(1024) k_topk(const float* __restrict__ logits,
                                               int* __restrict__ tki,
                                               float* __restrict__ tkw,
                                               float* __restrict__ counts) {
    int be = blockIdx.x;
    const float* row = logits + (size_t)be * S_;
    __shared__ unsigned long long keys[S_];
    __shared__ float wpart[16];
    __shared__ float stot;
    int tid = threadIdx.x;
    for (int i = tid; i < S_; i += 1024) {
        unsigned u = __float_as_uint(row[i]);
        u = (u & 0x80000000u) ? ~u : (u | 0x80000000u);
        keys[i] = ((unsigned long long)u << 32) | (unsigned)(~i);
    }
    __syncthreads();
    for (int k = 2; k <= S_; k <<= 1) {
        for (int j = k >> 1; j > 0; j >>= 1) {
#pragma unroll
            for (int base = 0; base < S_; base += 1024) {
                int i = base + tid;
                int ixj = i ^ j;
                if (ixj > i) {
                    unsigned long long a = keys[i], b = keys[ixj];
                    bool up = ((i & k) == 0);
                    bool sw = up ? (a < b) : (a > b);
                    if (sw) { keys[i] = b; keys[ixj] = a; }
                }
            }
            __syncthreads();
        }
    }
    int idx0 = (int)(~(unsigned)(keys[0] & 0xFFFFFFFFu));
    float vmax = row[idx0];
    int myidx = 0; float ex = 0.f;
    if (tid < CAP) {
        myidx = (int)(~(unsigned)(keys[tid] & 0xFFFFFFFFu));
        ex = expf(row[myidx] - vmax);
    }
    float v = ex;
#pragma unroll
    for (int off = 32; off > 0; off >>= 1) v += __shfl_down(v, off);
    if ((tid & 63) == 0) wpart[tid >> 6] = v;
    __syncthreads();
    if (tid == 0) {
        float s = 0.f;
#pragma unroll
        for (int i = 0; i < 16; ++i) s += wpart[i];
        stot = s;
    }
    __syncthreads();
    if (tid < CAP) {
        tki[be * CAP + tid] = myidx;
        tkw[be * CAP + tid] = ex / stot;
        atomicAdd(&counts[(be >> 3) * S_ + myidx], 1.0f);
    }
}

// ------------------------------------------------------------ conversions ---
__global__ void k_cvt_x(const float* __restrict__ in, f16* __restrict__ out) {
    size_t i = ((size_t)blockIdx.x * 256 + threadIdx.x) << 3;
    float4 a = *(const float4*)(in + i);
    float4 b = *(const float4*)(in + i + 4);
    f16x8 o = { (f16)a.x, (f16)a.y, (f16)a.z, (f16)a.w,
                (f16)b.x, (f16)b.y, (f16)b.z, (f16)b.w };
    *(f16x8*)(out + i) = o;
}

// in: [E][R][C] f32 → out: [E][C][R] f16
template<int R, int C>
__global__ void __launch_bounds__(256) k_transpose(const float* __restrict__ in,
                                                   f16* __restrict__ out) {
    __shared__ f16 t[64][68];
    int e = blockIdx.z;
    const float* ine = in + (size_t)e * R * C;
    f16* oute = out + (size_t)e * R * C;
    int c0 = blockIdx.x << 6, r0 = blockIdx.y << 6;
    int tx = threadIdx.x & 15, ty = threadIdx.x >> 4;
#pragma unroll
    for (int p = 0; p < 4; ++p) {
        int r = ty + p * 16;
        float4 v = *(const float4*)(ine + (size_t)(r0 + r) * C + c0 + tx * 4);
        t[tx * 4 + 0][r] = (f16)v.x;
        t[tx * 4 + 1][r] = (f16)v.y;
        t[tx * 4 + 2][r] = (f16)v.z;
        t[tx * 4 + 3][r] = (f16)v.w;
    }
    __syncthreads();
#pragma unroll
    for (int p = 0; p < 4; ++p) {
        int c = ty + p * 16;
        *(ushort4*)(oute + (size_t)(c0 + c) * R + r0 + tx * 4) =
            *(const ushort4*)&t[c][tx * 4];
    }
}

// ---------------------------------------------------------- GEMM1 (+SiLU) ---
// 128x128 tile, BK=32, f16 MFMA, 3-buffer LDS pipeline (2 tiles in flight),
// counted vmcnt(8) — loads span barriers (T3/T4).
__global__ void __launch_bounds__(256) k_gemm1(const f16* __restrict__ xh,
                                               const f16* __restrict__ w1t,
                                               const int* __restrict__ tki,
                                               f16* __restrict__ mid) {
    __shared__ f16 Al[3][4096];   // [128 m][32 k] per buffer, 16B-chunk swizzled
    __shared__ f16 Bl[3][4096];
    int rt = blockIdx.x, ct = blockIdx.y;
    int be = rt / 5, rq = rt - be * 5;
    int b = be >> 3, e = be & 7;
    int tid = threadIdx.x;
    int w = tid >> 6, l = tid & 63;
    // staging: lane covers (row = c*64 + w*16 + l/4, 16B slot = l&3);
    // swizzle: slot s of row r holds global k-chunk s ^ ((r>>2)&3) == s ^ (l>>4)
    int chunk = (l & 3) ^ (l >> 4);
    const f16* w1e = w1t + ((size_t)e << 22);
    int n0 = ct << 7;
    int row0 = w * 16 + (l >> 2);
    int tok0 = tki[be * CAP + rq * 128 + row0];
    int tok1 = tki[be * CAP + rq * 128 + 64 + row0];
    const f16* asrc0 = xh + (((size_t)(b * S_ + tok0)) << 10) + (chunk << 3);
    const f16* asrc1 = xh + (((size_t)(b * S_ + tok1)) << 10) + (chunk << 3);
    const f16* bsrc0 = w1e + (((size_t)(n0 + row0)) << 10) + (chunk << 3);
    const f16* bsrc1 = w1e + (((size_t)(n0 + 64 + row0)) << 10) + (chunk << 3);
    int dst0 = w * 512, dst1 = 2048 + w * 512;   // wave-uniform

    int wm = w >> 1, wn = w & 1;
    int fr = l & 15;
    int slot = (l >> 4) ^ ((l >> 2) & 3);        // read slot: g ^ ((r>>2)&3)
    int aoff[4], boff[4];
#pragma unroll
    for (int m = 0; m < 4; ++m) {
        aoff[m] = (wm * 64 + m * 16 + fr) * 32 + slot * 8;
        boff[m] = (wn * 64 + m * 16 + fr) * 32 + slot * 8;
    }
    f32x4 acc[4][4];
#pragma unroll
    for (int m = 0; m < 4; ++m)
#pragma unroll
        for (int n = 0; n < 4; ++n) acc[m][n] = (f32x4){0.f, 0.f, 0.f, 0.f};

#define STAGE1(P, KT) do { \
        gl_lds16(asrc0 + (size_t)(KT) * 32, &Al[P][dst0]); \
        gl_lds16(asrc1 + (size_t)(KT) * 32, &Al[P][dst1]); \
        gl_lds16(bsrc0 + (size_t)(KT) * 32, &Bl[P][dst0]); \
        gl_lds16(bsrc1 + (size_t)(KT) * 32, &Bl[P][dst1]); \
    } while (0)

    const int NT = H_ / 32;   // 32
    STAGE1(0, 0);
    STAGE1(1, 1);
    int p = 0;
    for (int t = 0; t < NT; ++t) {
        __builtin_amdgcn_sched_barrier(0);
        __builtin_amdgcn_s_barrier();            // WAR: prev iter's reads done
        int kn = t + 2; if (kn > NT - 1) kn = NT - 1;
        int pn = p + 2; if (pn >= 3) pn -= 3;
        STAGE1(pn, kn);
        asm volatile("s_waitcnt vmcnt(8)" ::: "memory");
        __builtin_amdgcn_s_barrier();            // RAW: buffer p landed
        f16x8 af[4], bf[4];
#pragma unroll
        for (int m = 0; m < 4; ++m) af[m] = *(const f16x8*)&Al[p][aoff[m]];
#pragma unroll
        for (int n = 0; n < 4; ++n) bf[n] = *(const f16x8*)&Bl[p][boff[n]];
#pragma unroll
        for (int m = 0; m < 4; ++m)
#pragma unroll
            for (int n = 0; n < 4; ++n)
                acc[m][n] = __builtin_amdgcn_mfma_f32_16x16x32_f16(af[m], bf[n], acc[m][n], 0, 0, 0);
        p = p + 1; if (p >= 3) p = 0;
    }
#undef STAGE1

    size_t rowbase = (size_t)be * CAP + rq * 128;
    int rq4 = (l >> 4) << 2;
#pragma unroll
    for (int m = 0; m < 4; ++m)
#pragma unroll
        for (int n = 0; n < 4; ++n)
#pragma unroll
            for (int q = 0; q < 4; ++q) {
                float v = acc[m][n][q];
                v = v / (1.f + expf(-v));
                int rr = wm * 64 + m * 16 + rq4 + q;
                int cc = n0 + wn * 64 + n * 16 + fr;
                mid[(rowbase + rr) * (size_t)I_ + cc] = (f16)v;
            }
}

// ------------------------------------------- GEMM2 + weighted atomic scatter
__global__ void __launch_bounds__(256) k_gemm2(const f16* __restrict__ mid,
                                               const f16* __restrict__ w2t,
                                               const int* __restrict__ tki,
                                               const float* __restrict__ tkw,
                                               float* __restrict__ out) {
    __shared__ f16 Al[3][4096];
    __shared__ f16 Bl[3][4096];
    __shared__ int   toksS[128];
    __shared__ float wtsS[128];
    int rt = blockIdx.x, ct = blockIdx.y;
    int be = rt / 5, rq = rt - be * 5;
    int b = be >> 3, e = be & 7;
    int tid = threadIdx.x;
    int w = tid >> 6, l = tid & 63;
    if (tid < 128) {
        toksS[tid] = tki[be * CAP + rq * 128 + tid];
        wtsS[tid]  = tkw[be * CAP + rq * 128 + tid];
    }
    int chunk = (l & 3) ^ (l >> 4);
    size_t rowbase = (size_t)be * CAP + rq * 128;
    const f16* w2e = w2t + ((size_t)e << 22);
    int n0 = ct << 7;
    int row0 = w * 16 + (l >> 2);
    const f16* asrc0 = mid + (rowbase + row0) * (size_t)I_ + (chunk << 3);
    const f16* asrc1 = mid + (rowbase + 64 + row0) * (size_t)I_ + (chunk << 3);
    const f16* bsrc0 = w2e + (((size_t)(n0 + row0)) << 12) + (chunk << 3);
    const f16* bsrc1 = w2e + (((size_t)(n0 + 64 + row0)) << 12) + (chunk << 3);
    int dst0 = w * 512, dst1 = 2048 + w * 512;

    int wm = w >> 1, wn = w & 1;
    int fr = l & 15;
    int slot = (l >> 4) ^ ((l >> 2) & 3);
    int aoff[4], boff[4];
#pragma unroll
    for (int m = 0; m < 4; ++m) {
        aoff[m] = (wm * 64 + m * 16 + fr) * 32 + slot * 8;
        boff[m] = (wn * 64 + m * 16 + fr) * 32 + slot * 8;
    }
    f32x4 acc[4][4];
#pragma unroll
    for (int m = 0; m < 4; ++m)
#pragma unroll
        for (int n = 0; n < 4; ++n) acc[m][n] = (f32x4){0.f, 0.f, 0.f, 0.f};

#define STAGE2(P, KT) do { \
        gl_lds16(asrc0 + (size_t)(KT) * 32, &Al[P][dst0]); \
        gl_lds16(asrc1 + (size_t)(KT) * 32, &Al[P][dst1]); \
        gl_lds16(bsrc0 + (size_t)(KT) * 32, &Bl[P][dst0]); \
        gl_lds16(bsrc1 + (size_t)(KT) * 32, &Bl[P][dst1]); \
    } while (0)

    const int NT = I_ / 32;   // 128
    STAGE2(0, 0);
    STAGE2(1, 1);
    int p = 0;
    for (int t = 0; t < NT; ++t) {
        __builtin_amdgcn_sched_barrier(0);
        __builtin_amdgcn_s_barrier();
        int kn = t + 2; if (kn > NT - 1) kn = NT - 1;
        int pn = p + 2; if (pn >= 3) pn -= 3;
        STAGE2(pn, kn);
        asm volatile("s_waitcnt vmcnt(8)" ::: "memory");
        __builtin_amdgcn_s_barrier();
        f16x8 af[4], bf[4];
#pragma unroll
        for (int m = 0; m < 4; ++m) af[m] = *(const f16x8*)&Al[p][aoff[m]];
#pragma unroll
        for (int n = 0; n < 4; ++n) bf[n] = *(const f16x8*)&Bl[p][boff[n]];
#pragma unroll
        for (int m = 0; m < 4; ++m)
#pragma unroll
            for (int n = 0; n < 4; ++n)
                acc[m][n] = __builtin_amdgcn_mfma_f32_16x16x32_f16(af[m], bf[n], acc[m][n], 0, 0, 0);
        p = p + 1; if (p >= 3) p = 0;
    }
#undef STAGE2

    int rq4 = (l >> 4) << 2;
#pragma unroll
    for (int m = 0; m < 4; ++m)
#pragma unroll
        for (int n = 0; n < 4; ++n)
#pragma unroll
            for (int q = 0; q < 4; ++q) {
                int rr = wm * 64 + m * 16 + rq4 + q;
                int cc = n0 + wn * 64 + n * 16 + fr;
                int token = toksS[rr];
                float wgt = wtsS[rr];
                atomicAdd(&out[((size_t)(b * S_ + token) << 10) + cc],
                          acc[m][n][q] * wgt);
            }
}

// ------------------------------------------------- normalize + loss ---------
__global__ void k_final(float* __restrict__ out, const float* __restrict__ counts,
                        const float* __restrict__ scal, float* __restrict__ loss_out) {
    size_t gid = (size_t)blockIdx.x * 256 + threadIdx.x;
    int tok = (int)(gid >> 8);
    float c = fmaxf(counts[tok], 1.0f);
    float4* o4 = (float4*)out;
    float4 v = o4[gid];
    v.x /= c; v.y /= c; v.z /= c; v.w /= c;
    o4[gid] = v;
    if (gid == 0) {
        float z = scal[0] / (float)(NTOK * E_);
        float aux = 0.f;
#pragma unroll
        for (int e = 0; e < E_; ++e) {
            float u = scal[1 + e] / (float)NTOK - 0.125f;
            aux += u * u;
        }
        loss_out[0] = 0.01f * aux + 0.001f * z;
    }
}

// ----------------------------------------------------------------------------
extern "C" void kernel_launch(void* const* d_in, const int* in_sizes, int n_in,
                              void* d_out, int out_size, void* d_ws, size_t ws_size,
                              hipStream_t stream) {
    const float* x  = (const float*)d_in[0];
    const float* rw = (const float*)d_in[1];
    const float* w1 = (const float*)d_in[2];
    const float* w2 = (const float*)d_in[3];
    float* out = (float*)d_out;
    char* ws = (char*)d_ws;

    float* logits = (float*)(ws + OFF_LOGITS);
    int*   tki    = (int*)(ws + OFF_TOPKI);
    float* tkw    = (float*)(ws + OFF_TOPKW);
    float* counts = (float*)(ws + OFF_COUNTS);
    float* scal   = (float*)(ws + OFF_SCAL);
    f16*   xh     = (f16*)(ws + OFF_XH);
    f16*   wt     = (f16*)(ws + OFF_WT);     // w1t, then reused as w2t
    f16*   mid    = (f16*)(ws + OFF_MID);

    hipMemsetAsync(ws + OFF_COUNTS, 0, 64u * 1024u + 64u, stream);
    hipMemsetAsync(d_out, 0, (size_t)out_size * sizeof(float), stream);

    k_cvt_x<<<NTOK * H_ / 8 / 256, 256, 0, stream>>>(x, xh);
    k_transpose<H_, I_><<<dim3(I_ / 64, H_ / 64, E_), 256, 0, stream>>>(w1, wt);
    k_router<<<NTOK / 4, 256, 0, stream>>>(x, rw, logits, scal);
    k_topk<<<NBE, 1024, 0, stream>>>(logits, tki, tkw, counts);
    k_gemm1<<<dim3(NBE * 5, I_ / 128), 256, 0, stream>>>(xh, wt, tki, mid);
    // reuse WT region for w2t (stream-ordered after gemm1 finished reading w1t)
    k_transpose<I_, H_><<<dim3(H_ / 64, I_ / 64, E_), 256, 0, stream>>>(w2, wt);
    k_gemm2<<<dim3(NBE * 5, H_ / 128), 256, 0, stream>>>(mid, wt, tki, tkw, out);
    k_final<<<(NTOK * H_ / 4) / 256, 256, 0, stream>>>(out, counts, scal,
                                                       out + (size_t)NTOK * H_);
}

// Round 4
// 714.924 us; speedup vs baseline: 1.0244x; 1.0244x over previous
//
#include <hip/hip_runtime.h>
#include <hip/hip_bf16.h>
#include <stdint.h>

#define B_ 4
#define S_ 2048
#define H_ 1024
#define I_ 4096
#define E_ 8
#define CAP 640
#define NTOK (B_*S_)            // 8192
#define NBE  (B_*E_)            // 32

typedef _Float16 f16;
typedef f16 f16x8 __attribute__((ext_vector_type(8)));
typedef float f32x4 __attribute__((ext_vector_type(4)));

// workspace layout (bytes)
#define OFF_LOGITS 0u                          // 65536 f32
#define OFF_TOPKI  (256u*1024u)                // 20480 int
#define OFF_TOPKW  (OFF_TOPKI + 128u*1024u)    // 20480 f32
#define OFF_COUNTS (OFF_TOPKW + 128u*1024u)    // 8192 f32
#define OFF_SCAL   (OFF_COUNTS + 64u*1024u)    // 16 f32
#define OFF_XH     (1u<<20)                    // 8192*1024 f16   (16.8 MB)
#define OFF_WT     (18u<<20)                   // 8*4096*1024 f16 (67.1 MB) — w1t then w2t (reused)
#define OFF_MID    (86u<<20)                   // 20480*4096 f16  (167.8 MB) → high-water ~254 MB

__device__ __forceinline__ void gl_lds16(const void* g, void* l) {
    __builtin_amdgcn_global_load_lds(
        (const __attribute__((address_space(1))) uint32_t*)g,
        (__attribute__((address_space(3))) uint32_t*)l, 16, 0, 0);
}

// ---------------------------------------------------------------- router ----
// NOTE: summation order is frozen — top-k selection depends on exact fp32
// logit ordering near capacity boundaries. Do not restructure this reduce.
__global__ void k_router(const float* __restrict__ x, const float* __restrict__ rw,
                         float* __restrict__ logits, float* __restrict__ scal) {
    __shared__ float rwt[E_ * H_];
    __shared__ float part[4][9];
    int tid = threadIdx.x;
    for (int i = tid; i < E_ * H_; i += 256) {
        int h = i >> 3, e = i & 7;
        rwt[e * H_ + h] = rw[i];
    }
    __syncthreads();
    int w = tid >> 6, lane = tid & 63;
    int t = blockIdx.x * 4 + w;
    const float* xr = x + (size_t)t * H_;
    float acc[E_];
#pragma unroll
    for (int e = 0; e < E_; ++e) acc[e] = 0.f;
    for (int it = 0; it < H_ / 64; ++it) {
        int h = lane + it * 64;
        float xv = xr[h];
#pragma unroll
        for (int e = 0; e < E_; ++e) acc[e] += xv * rwt[e * H_ + h];
    }
#pragma unroll
    for (int off = 32; off > 0; off >>= 1)
#pragma unroll
        for (int e = 0; e < E_; ++e) acc[e] += __shfl_down(acc[e], off);
    if (lane == 0) {
        int b = t >> 11, s = t & 2047;
        float m = acc[0];
#pragma unroll
        for (int e = 1; e < E_; ++e) m = fmaxf(m, acc[e]);
        float z = 0.f, ps = 0.f;
        float p[E_];
#pragma unroll
        for (int e = 0; e < E_; ++e) {
            logits[(size_t)((b << 3) + e) * S_ + s] = acc[e];
            z += acc[e] * acc[e];
            p[e] = expf(acc[e] - m);
            ps += p[e];
        }
        part[w][0] = z;
#pragma unroll
        for (int e = 0; e < E_; ++e) part[w][1 + e] = p[e] / ps;
    }
    __syncthreads();
    if (tid < 9) {
        float v = part[0][tid] + part[1][tid] + part[2][tid] + part[3][tid];
        atomicAdd(&scal[tid], v);
    }
}

// ----------------------------------------------------------------- top-k ----
__global__ void __launch_bounds__(1024) k_topk(const float* __restrict__ logits,
                                               int* __restrict__ tki,
                                               float* __restrict__ tkw,
                                               float* __restrict__ counts) {
    int be = blockIdx.x;
    const float* row = logits + (size_t)be * S_;
    __shared__ unsigned long long keys[S_];
    __shared__ float wpart[16];
    __shared__ float stot;
    int tid = threadIdx.x;
    for (int i = tid; i < S_; i += 1024) {
        unsigned u = __float_as_uint(row[i]);
        u = (u & 0x80000000u) ? ~u : (u | 0x80000000u);
        keys[i] = ((unsigned long long)u << 32) | (unsigned)(~i);
    }
    __syncthreads();
    for (int k = 2; k <= S_; k <<= 1) {
        for (int j = k >> 1; j > 0; j >>= 1) {
#pragma unroll
            for (int base = 0; base < S_; base += 1024) {
                int i = base + tid;
                int ixj = i ^ j;
                if (ixj > i) {
                    unsigned long long a = keys[i], b = keys[ixj];
                    bool up = ((i & k) == 0);
                    bool sw = up ? (a < b) : (a > b);
                    if (sw) { keys[i] = b; keys[ixj] = a; }
                }
            }
            __syncthreads();
        }
    }
    int idx0 = (int)(~(unsigned)(keys[0] & 0xFFFFFFFFu));
    float vmax = row[idx0];
    int myidx = 0; float ex = 0.f;
    if (tid < CAP) {
        myidx = (int)(~(unsigned)(keys[tid] & 0xFFFFFFFFu));
        ex = expf(row[myidx] - vmax);
    }
    float v = ex;
#pragma unroll
    for (int off = 32; off > 0; off >>= 1) v += __shfl_down(v, off);
    if ((tid & 63) == 0) wpart[tid >> 6] = v;
    __syncthreads();
    if (tid == 0) {
        float s = 0.f;
#pragma unroll
        for (int i = 0; i < 16; ++i) s += wpart[i];
        stot = s;
    }
    __syncthreads();
    if (tid < CAP) {
        tki[be * CAP + tid] = myidx;
        tkw[be * CAP + tid] = ex / stot;
        atomicAdd(&counts[(be >> 3) * S_ + myidx], 1.0f);
    }
}

// ------------------------------------------------------------ conversions ---
__global__ void k_cvt_x(const float* __restrict__ in, f16* __restrict__ out) {
    size_t i = ((size_t)blockIdx.x * 256 + threadIdx.x) << 3;
    float4 a = *(const float4*)(in + i);
    float4 b = *(const float4*)(in + i + 4);
    f16x8 o = { (f16)a.x, (f16)a.y, (f16)a.z, (f16)a.w,
                (f16)b.x, (f16)b.y, (f16)b.z, (f16)b.w };
    *(f16x8*)(out + i) = o;
}

// in: [E][R][C] f32 → out: [E][C][R] f16
template<int R, int C>
__global__ void __launch_bounds__(256) k_transpose(const float* __restrict__ in,
                                                   f16* __restrict__ out) {
    __shared__ f16 t[64][68];
    int e = blockIdx.z;
    const float* ine = in + (size_t)e * R * C;
    f16* oute = out + (size_t)e * R * C;
    int c0 = blockIdx.x << 6, r0 = blockIdx.y << 6;
    int tx = threadIdx.x & 15, ty = threadIdx.x >> 4;
#pragma unroll
    for (int p = 0; p < 4; ++p) {
        int r = ty + p * 16;
        float4 v = *(const float4*)(ine + (size_t)(r0 + r) * C + c0 + tx * 4);
        t[tx * 4 + 0][r] = (f16)v.x;
        t[tx * 4 + 1][r] = (f16)v.y;
        t[tx * 4 + 2][r] = (f16)v.z;
        t[tx * 4 + 3][r] = (f16)v.w;
    }
    __syncthreads();
#pragma unroll
    for (int p = 0; p < 4; ++p) {
        int c = ty + p * 16;
        *(ushort4*)(oute + (size_t)(c0 + c) * R + r0 + tx * 4) =
            *(const ushort4*)&t[c][tx * 4];
    }
}

// ============================ GEMM core geometry =============================
// Block: 256 thr (4 waves). Tile: M=128, N=256. Wave w owns 128x64 (n = w*64).
// BK=32, 3 LDS buffers, distance-2 prefetch, 2 phases/K-tile, vmcnt(6).
// LDS swizzle: 16B chunk s of row r stored at slot s ^ ((r>>2)&3).

// ---------------------------------------------------------- GEMM1 (+SiLU) ---
__global__ void __launch_bounds__(256, 2) k_gemm1(const f16* __restrict__ xh,
                                                  const f16* __restrict__ w1t,
                                                  const int* __restrict__ tki,
                                                  f16* __restrict__ mid) {
    __shared__ f16 Ab[3 * 128 * 32];   // 24 KB
    __shared__ f16 Bb[3 * 256 * 32];   // 48 KB
    int rt = blockIdx.x, ct = blockIdx.y;
    int be = rt / 5, rq = rt - be * 5;
    int b = be >> 3, e = be & 7;
    int tid = threadIdx.x;
    int w = tid >> 6, l = tid & 63;
    int n0 = ct << 8;
    size_t rowTK = (size_t)be * CAP + rq * 128;
    // staging: dest = buf + tid*16B (+ q*2048 elem); row = q*64 + tid/4, slot = tid&3
    int chunk = (tid & 3) ^ ((tid >> 4) & 3);
    int srow = tid >> 2;
    const f16* w1e = w1t + ((size_t)e << 22);
    int tokA = tki[rowTK + srow];
    int tokB = tki[rowTK + 64 + srow];
    const f16* asrc0 = xh + (((size_t)(b * S_ + tokA)) << 10) + (chunk << 3);
    const f16* asrc1 = xh + (((size_t)(b * S_ + tokB)) << 10) + (chunk << 3);
    const f16* bsrcB = w1e + (((size_t)(n0 + srow)) << 10) + (chunk << 3);
    int dstoff = tid << 3;

    int fr = l & 15;
    int slotR = (l >> 4) ^ ((fr >> 2) & 3);
    int aoff = fr * 32 + slotR * 8;                 // + mi*512
    int boff = (w * 64 + fr) * 32 + slotR * 8;      // + ni*512

    f32x4 acc[8][4];
#pragma unroll
    for (int mi = 0; mi < 8; ++mi)
#pragma unroll
        for (int ni = 0; ni < 4; ++ni) acc[mi][ni] = (f32x4){0.f, 0.f, 0.f, 0.f};

#define STAGEA1(AB, KT) do { \
        gl_lds16(asrc0 + ((KT) << 5), (AB) + dstoff); \
        gl_lds16(asrc1 + ((KT) << 5), (AB) + dstoff + 2048); } while (0)
#define STAGEB01_1(BB, KT) do { \
        gl_lds16(bsrcB + ((KT) << 5),               (BB) + dstoff); \
        gl_lds16(bsrcB + ((KT) << 5) + (64 << 10),  (BB) + dstoff + 2048); } while (0)
#define STAGEB23_1(BB, KT) do { \
        gl_lds16(bsrcB + ((KT) << 5) + (128 << 10), (BB) + dstoff + 4096); \
        gl_lds16(bsrcB + ((KT) << 5) + (192 << 10), (BB) + dstoff + 6144); } while (0)

    const int NT = H_ / 32;   // 32
    STAGEA1(Ab, 0); STAGEB01_1(Bb, 0); STAGEB23_1(Bb, 0);
    STAGEA1(Ab + 4096, 1); STAGEB01_1(Bb + 8192, 1); STAGEB23_1(Bb + 8192, 1);
    asm volatile("s_waitcnt vmcnt(6)" ::: "memory");
    __builtin_amdgcn_s_barrier();

    int cur = 0;
    for (int t = 0; t < NT; ++t) {
        int kt = t + 2; if (kt > NT - 1) kt = NT - 1;
        int nxt = cur + 2; if (nxt >= 3) nxt -= 3;
        const f16* Ac = Ab + cur * 4096;
        const f16* Bc = Bb + cur * 8192;
        f16* An = Ab + nxt * 4096;
        f16* Bn = Bb + nxt * 8192;
        // ---- phase 0: A mi0-3 + all B; stage A + B01 of t+2; MFMA quad 0
        f16x8 af0 = *(const f16x8*)(Ac + aoff);
        f16x8 af1 = *(const f16x8*)(Ac + aoff + 512);
        f16x8 af2 = *(const f16x8*)(Ac + aoff + 1024);
        f16x8 af3 = *(const f16x8*)(Ac + aoff + 1536);
        f16x8 bf0 = *(const f16x8*)(Bc + boff);
        f16x8 bf1 = *(const f16x8*)(Bc + boff + 512);
        f16x8 bf2 = *(const f16x8*)(Bc + boff + 1024);
        f16x8 bf3 = *(const f16x8*)(Bc + boff + 1536);
        STAGEA1(An, kt); STAGEB01_1(Bn, kt);
        __builtin_amdgcn_s_setprio(1);
        acc[0][0] = __builtin_amdgcn_mfma_f32_16x16x32_f16(af0, bf0, acc[0][0], 0, 0, 0);
        acc[0][1] = __builtin_amdgcn_mfma_f32_16x16x32_f16(af0, bf1, acc[0][1], 0, 0, 0);
        acc[0][2] = __builtin_amdgcn_mfma_f32_16x16x32_f16(af0, bf2, acc[0][2], 0, 0, 0);
        acc[0][3] = __builtin_amdgcn_mfma_f32_16x16x32_f16(af0, bf3, acc[0][3], 0, 0, 0);
        acc[1][0] = __builtin_amdgcn_mfma_f32_16x16x32_f16(af1, bf0, acc[1][0], 0, 0, 0);
        acc[1][1] = __builtin_amdgcn_mfma_f32_16x16x32_f16(af1, bf1, acc[1][1], 0, 0, 0);
        acc[1][2] = __builtin_amdgcn_mfma_f32_16x16x32_f16(af1, bf2, acc[1][2], 0, 0, 0);
        acc[1][3] = __builtin_amdgcn_mfma_f32_16x16x32_f16(af1, bf3, acc[1][3], 0, 0, 0);
        acc[2][0] = __builtin_amdgcn_mfma_f32_16x16x32_f16(af2, bf0, acc[2][0], 0, 0, 0);
        acc[2][1] = __builtin_amdgcn_mfma_f32_16x16x32_f16(af2, bf1, acc[2][1], 0, 0, 0);
        acc[2][2] = __builtin_amdgcn_mfma_f32_16x16x32_f16(af2, bf2, acc[2][2], 0, 0, 0);
        acc[2][3] = __builtin_amdgcn_mfma_f32_16x16x32_f16(af2, bf3, acc[2][3], 0, 0, 0);
        acc[3][0] = __builtin_amdgcn_mfma_f32_16x16x32_f16(af3, bf0, acc[3][0], 0, 0, 0);
        acc[3][1] = __builtin_amdgcn_mfma_f32_16x16x32_f16(af3, bf1, acc[3][1], 0, 0, 0);
        acc[3][2] = __builtin_amdgcn_mfma_f32_16x16x32_f16(af3, bf2, acc[3][2], 0, 0, 0);
        acc[3][3] = __builtin_amdgcn_mfma_f32_16x16x32_f16(af3, bf3, acc[3][3], 0, 0, 0);
        __builtin_amdgcn_s_setprio(0);
        __builtin_amdgcn_s_barrier();
        // ---- phase 1: A mi4-7; stage B23 of t+2; MFMA quad 1
        f16x8 af4 = *(const f16x8*)(Ac + aoff + 2048);
        f16x8 af5 = *(const f16x8*)(Ac + aoff + 2560);
        f16x8 af6 = *(const f16x8*)(Ac + aoff + 3072);
        f16x8 af7 = *(const f16x8*)(Ac + aoff + 3584);
        STAGEB23_1(Bn, kt);
        __builtin_amdgcn_s_setprio(1);
        acc[4][0] = __builtin_amdgcn_mfma_f32_16x16x32_f16(af4, bf0, acc[4][0], 0, 0, 0);
        acc[4][1] = __builtin_amdgcn_mfma_f32_16x16x32_f16(af4, bf1, acc[4][1], 0, 0, 0);
        acc[4][2] = __builtin_amdgcn_mfma_f32_16x16x32_f16(af4, bf2, acc[4][2], 0, 0, 0);
        acc[4][3] = __builtin_amdgcn_mfma_f32_16x16x32_f16(af4, bf3, acc[4][3], 0, 0, 0);
        acc[5][0] = __builtin_amdgcn_mfma_f32_16x16x32_f16(af5, bf0, acc[5][0], 0, 0, 0);
        acc[5][1] = __builtin_amdgcn_mfma_f32_16x16x32_f16(af5, bf1, acc[5][1], 0, 0, 0);
        acc[5][2] = __builtin_amdgcn_mfma_f32_16x16x32_f16(af5, bf2, acc[5][2], 0, 0, 0);
        acc[5][3] = __builtin_amdgcn_mfma_f32_16x16x32_f16(af5, bf3, acc[5][3], 0, 0, 0);
        acc[6][0] = __builtin_amdgcn_mfma_f32_16x16x32_f16(af6, bf0, acc[6][0], 0, 0, 0);
        acc[6][1] = __builtin_amdgcn_mfma_f32_16x16x32_f16(af6, bf1, acc[6][1], 0, 0, 0);
        acc[6][2] = __builtin_amdgcn_mfma_f32_16x16x32_f16(af6, bf2, acc[6][2], 0, 0, 0);
        acc[6][3] = __builtin_amdgcn_mfma_f32_16x16x32_f16(af6, bf3, acc[6][3], 0, 0, 0);
        acc[7][0] = __builtin_amdgcn_mfma_f32_16x16x32_f16(af7, bf0, acc[7][0], 0, 0, 0);
        acc[7][1] = __builtin_amdgcn_mfma_f32_16x16x32_f16(af7, bf1, acc[7][1], 0, 0, 0);
        acc[7][2] = __builtin_amdgcn_mfma_f32_16x16x32_f16(af7, bf2, acc[7][2], 0, 0, 0);
        acc[7][3] = __builtin_amdgcn_mfma_f32_16x16x32_f16(af7, bf3, acc[7][3], 0, 0, 0);
        __builtin_amdgcn_s_setprio(0);
        asm volatile("s_waitcnt vmcnt(6)" ::: "memory");
        __builtin_amdgcn_s_barrier();
        cur += 1; if (cur >= 3) cur -= 3;
    }
#undef STAGEA1
#undef STAGEB01_1
#undef STAGEB23_1

    int rq4 = (l >> 4) << 2;
#pragma unroll
    for (int mi = 0; mi < 8; ++mi)
#pragma unroll
        for (int ni = 0; ni < 4; ++ni)
#pragma unroll
            for (int q = 0; q < 4; ++q) {
                float v = acc[mi][ni][q];
                v = v / (1.f + expf(-v));
                int rr = mi * 16 + rq4 + q;
                int cc = n0 + w * 64 + ni * 16 + fr;
                mid[(rowTK + rr) * (size_t)I_ + cc] = (f16)v;
            }
}

// ------------------------------------------- GEMM2 + weighted atomic scatter
__global__ void __launch_bounds__(256, 2) k_gemm2(const f16* __restrict__ mid,
                                                  const f16* __restrict__ w2t,
                                                  const int* __restrict__ tki,
                                                  const float* __restrict__ tkw,
                                                  float* __restrict__ out) {
    __shared__ f16 Ab[3 * 128 * 32];
    __shared__ f16 Bb[3 * 256 * 32];
    __shared__ int   toksS[128];
    __shared__ float wtsS[128];
    int rt = blockIdx.x, ct = blockIdx.y;
    int be = rt / 5, rq = rt - be * 5;
    int b = be >> 3, e = be & 7;
    int tid = threadIdx.x;
    int w = tid >> 6, l = tid & 63;
    int n0 = ct << 8;
    size_t rowTK = (size_t)be * CAP + rq * 128;
    if (tid < 128) {
        toksS[tid] = tki[rowTK + tid];
        wtsS[tid]  = tkw[rowTK + tid];
    }
    int chunk = (tid & 3) ^ ((tid >> 4) & 3);
    int srow = tid >> 2;
    const f16* w2e = w2t + ((size_t)e << 22);
    const f16* asrc0 = mid + ((rowTK + srow) << 12) + (chunk << 3);
    const f16* asrc1 = mid + ((rowTK + 64 + srow) << 12) + (chunk << 3);
    const f16* bsrcB = w2e + (((size_t)(n0 + srow)) << 12) + (chunk << 3);
    int dstoff = tid << 3;

    int fr = l & 15;
    int slotR = (l >> 4) ^ ((fr >> 2) & 3);
    int aoff = fr * 32 + slotR * 8;
    int boff = (w * 64 + fr) * 32 + slotR * 8;

    f32x4 acc[8][4];
#pragma unroll
    for (int mi = 0; mi < 8; ++mi)
#pragma unroll
        for (int ni = 0; ni < 4; ++ni) acc[mi][ni] = (f32x4){0.f, 0.f, 0.f, 0.f};

#define STAGEA2(AB, KT) do { \
        gl_lds16(asrc0 + ((KT) << 5), (AB) + dstoff); \
        gl_lds16(asrc1 + ((KT) << 5), (AB) + dstoff + 2048); } while (0)
#define STAGEB01_2(BB, KT) do { \
        gl_lds16(bsrcB + ((KT) << 5),               (BB) + dstoff); \
        gl_lds16(bsrcB + ((KT) << 5) + (64 << 12),  (BB) + dstoff + 2048); } while (0)
#define STAGEB23_2(BB, KT) do { \
        gl_lds16(bsrcB + ((KT) << 5) + (128 << 12), (BB) + dstoff + 4096); \
        gl_lds16(bsrcB + ((KT) << 5) + (192 << 12), (BB) + dstoff + 6144); } while (0)

    const int NT = I_ / 32;   // 128
    STAGEA2(Ab, 0); STAGEB01_2(Bb, 0); STAGEB23_2(Bb, 0);
    STAGEA2(Ab + 4096, 1); STAGEB01_2(Bb + 8192, 1); STAGEB23_2(Bb + 8192, 1);
    asm volatile("s_waitcnt vmcnt(6)" ::: "memory");
    __builtin_amdgcn_s_barrier();

    int cur = 0;
    for (int t = 0; t < NT; ++t) {
        int kt = t + 2; if (kt > NT - 1) kt = NT - 1;
        int nxt = cur + 2; if (nxt >= 3) nxt -= 3;
        const f16* Ac = Ab + cur * 4096;
        const f16* Bc = Bb + cur * 8192;
        f16* An = Ab + nxt * 4096;
        f16* Bn = Bb + nxt * 8192;
        f16x8 af0 = *(const f16x8*)(Ac + aoff);
        f16x8 af1 = *(const f16x8*)(Ac + aoff + 512);
        f16x8 af2 = *(const f16x8*)(Ac + aoff + 1024);
        f16x8 af3 = *(const f16x8*)(Ac + aoff + 1536);
        f16x8 bf0 = *(const f16x8*)(Bc + boff);
        f16x8 bf1 = *(const f16x8*)(Bc + boff + 512);
        f16x8 bf2 = *(const f16x8*)(Bc + boff + 1024);
        f16x8 bf3 = *(const f16x8*)(Bc + boff + 1536);
        STAGEA2(An, kt); STAGEB01_2(Bn, kt);
        __builtin_amdgcn_s_setprio(1);
        acc[0][0] = __builtin_amdgcn_mfma_f32_16x16x32_f16(af0, bf0, acc[0][0], 0, 0, 0);
        acc[0][1] = __builtin_amdgcn_mfma_f32_16x16x32_f16(af0, bf1, acc[0][1], 0, 0, 0);
        acc[0][2] = __builtin_amdgcn_mfma_f32_16x16x32_f16(af0, bf2, acc[0][2], 0, 0, 0);
        acc[0][3] = __builtin_amdgcn_mfma_f32_16x16x32_f16(af0, bf3, acc[0][3], 0, 0, 0);
        acc[1][0] = __builtin_amdgcn_mfma_f32_16x16x32_f16(af1, bf0, acc[1][0], 0, 0, 0);
        acc[1][1] = __builtin_amdgcn_mfma_f32_16x16x32_f16(af1, bf1, acc[1][1], 0, 0, 0);
        acc[1][2] = __builtin_amdgcn_mfma_f32_16x16x32_f16(af1, bf2, acc[1][2], 0, 0, 0);
        acc[1][3] = __builtin_amdgcn_mfma_f32_16x16x32_f16(af1, bf3, acc[1][3], 0, 0, 0);
        acc[2][0] = __builtin_amdgcn_mfma_f32_16x16x32_f16(af2, bf0, acc[2][0], 0, 0, 0);
        acc[2][1] = __builtin_amdgcn_mfma_f32_16x16x32_f16(af2, bf1, acc[2][1], 0, 0, 0);
        acc[2][2] = __builtin_amdgcn_mfma_f32_16x16x32_f16(af2, bf2, acc[2][2], 0, 0, 0);
        acc[2][3] = __builtin_amdgcn_mfma_f32_16x16x32_f16(af2, bf3, acc[2][3], 0, 0, 0);
        acc[3][0] = __builtin_amdgcn_mfma_f32_16x16x32_f16(af3, bf0, acc[3][0], 0, 0, 0);
        acc[3][1] = __builtin_amdgcn_mfma_f32_16x16x32_f16(af3, bf1, acc[3][1], 0, 0, 0);
        acc[3][2] = __builtin_amdgcn_mfma_f32_16x16x32_f16(af3, bf2, acc[3][2], 0, 0, 0);
        acc[3][3] = __builtin_amdgcn_mfma_f32_16x16x32_f16(af3, bf3, acc[3][3], 0, 0, 0);
        __builtin_amdgcn_s_setprio(0);
        __builtin_amdgcn_s_barrier();
        f16x8 af4 = *(const f16x8*)(Ac + aoff + 2048);
        f16x8 af5 = *(const f16x8*)(Ac + aoff + 2560);
        f16x8 af6 = *(const f16x8*)(Ac + aoff + 3072);
        f16x8 af7 = *(const f16x8*)(Ac + aoff + 3584);
        STAGEB23_2(Bn, kt);
        __builtin_amdgcn_s_setprio(1);
        acc[4][0] = __builtin_amdgcn_mfma_f32_16x16x32_f16(af4, bf0, acc[4][0], 0, 0, 0);
        acc[4][1] = __builtin_amdgcn_mfma_f32_16x16x32_f16(af4, bf1, acc[4][1], 0, 0, 0);
        acc[4][2] = __builtin_amdgcn_mfma_f32_16x16x32_f16(af4, bf2, acc[4][2], 0, 0, 0);
        acc[4][3] = __builtin_amdgcn_mfma_f32_16x16x32_f16(af4, bf3, acc[4][3], 0, 0, 0);
        acc[5][0] = __builtin_amdgcn_mfma_f32_16x16x32_f16(af5, bf0, acc[5][0], 0, 0, 0);
        acc[5][1] = __builtin_amdgcn_mfma_f32_16x16x32_f16(af5, bf1, acc[5][1], 0, 0, 0);
        acc[5][2] = __builtin_amdgcn_mfma_f32_16x16x32_f16(af5, bf2, acc[5][2], 0, 0, 0);
        acc[5][3] = __builtin_amdgcn_mfma_f32_16x16x32_f16(af5, bf3, acc[5][3], 0, 0, 0);
        acc[6][0] = __builtin_amdgcn_mfma_f32_16x16x32_f16(af6, bf0, acc[6][0], 0, 0, 0);
        acc[6][1] = __builtin_amdgcn_mfma_f32_16x16x32_f16(af6, bf1, acc[6][1], 0, 0, 0);
        acc[6][2] = __builtin_amdgcn_mfma_f32_16x16x32_f16(af6, bf2, acc[6][2], 0, 0, 0);
        acc[6][3] = __builtin_amdgcn_mfma_f32_16x16x32_f16(af6, bf3, acc[6][3], 0, 0, 0);
        acc[7][0] = __builtin_amdgcn_mfma_f32_16x16x32_f16(af7, bf0, acc[7][0], 0, 0, 0);
        acc[7][1] = __builtin_amdgcn_mfma_f32_16x16x32_f16(af7, bf1, acc[7][1], 0, 0, 0);
        acc[7][2] = __builtin_amdgcn_mfma_f32_16x16x32_f16(af7, bf2, acc[7][2], 0, 0, 0);
        acc[7][3] = __builtin_amdgcn_mfma_f32_16x16x32_f16(af7, bf3, acc[7][3], 0, 0, 0);
        __builtin_amdgcn_s_setprio(0);
        asm volatile("s_waitcnt vmcnt(6)" ::: "memory");
        __builtin_amdgcn_s_barrier();
        cur += 1; if (cur >= 3) cur -= 3;
    }
#undef STAGEA2
#undef STAGEB01_2
#undef STAGEB23_2

    int rq4 = (l >> 4) << 2;
#pragma unroll
    for (int mi = 0; mi < 8; ++mi)
#pragma unroll
        for (int ni = 0; ni < 4; ++ni)
#pragma unroll
            for (int q = 0; q < 4; ++q) {
                int rr = mi * 16 + rq4 + q;
                int cc = n0 + w * 64 + ni * 16 + fr;
                int token = toksS[rr];
                float wgt = wtsS[rr];
                atomicAdd(&out[((size_t)(b * S_ + token) << 10) + cc],
                          acc[mi][ni][q] * wgt);
            }
}

// ------------------------------------------------- normalize + loss ---------
__global__ void k_final(float* __restrict__ out, const float* __restrict__ counts,
                        const float* __restrict__ scal, float* __restrict__ loss_out) {
    size_t gid = (size_t)blockIdx.x * 256 + threadIdx.x;
    int tok = (int)(gid >> 8);
    float c = fmaxf(counts[tok], 1.0f);
    float4* o4 = (float4*)out;
    float4 v = o4[gid];
    v.x /= c; v.y /= c; v.z /= c; v.w /= c;
    o4[gid] = v;
    if (gid == 0) {
        float z = scal[0] / (float)(NTOK * E_);
        float aux = 0.f;
#pragma unroll
        for (int e = 0; e < E_; ++e) {
            float u = scal[1 + e] / (float)NTOK - 0.125f;
            aux += u * u;
        }
        loss_out[0] = 0.01f * aux + 0.001f * z;
    }
}

// ----------------------------------------------------------------------------
extern "C" void kernel_launch(void* const* d_in, const int* in_sizes, int n_in,
                              void* d_out, int out_size, void* d_ws, size_t ws_size,
                              hipStream_t stream) {
    const float* x  = (const float*)d_in[0];
    const float* rw = (const float*)d_in[1];
    const float* w1 = (const float*)d_in[2];
    const float* w2 = (const float*)d_in[3];
    float* out = (float*)d_out;
    char* ws = (char*)d_ws;

    float* logits = (float*)(ws + OFF_LOGITS);
    int*   tki    = (int*)(ws + OFF_TOPKI);
    float* tkw    = (float*)(ws + OFF_TOPKW);
    float* counts = (float*)(ws + OFF_COUNTS);
    float* scal   = (float*)(ws + OFF_SCAL);
    f16*   xh     = (f16*)(ws + OFF_XH);
    f16*   wt     = (f16*)(ws + OFF_WT);     // w1t, then reused as w2t
    f16*   mid    = (f16*)(ws + OFF_MID);

    hipMemsetAsync(ws + OFF_COUNTS, 0, 64u * 1024u + 64u, stream);
    hipMemsetAsync(d_out, 0, (size_t)out_size * sizeof(float), stream);

    k_cvt_x<<<NTOK * H_ / 8 / 256, 256, 0, stream>>>(x, xh);
    k_transpose<H_, I_><<<dim3(I_ / 64, H_ / 64, E_), 256, 0, stream>>>(w1, wt);
    k_router<<<NTOK / 4, 256, 0, stream>>>(x, rw, logits, scal);
    k_topk<<<NBE, 1024, 0, stream>>>(logits, tki, tkw, counts);
    k_gemm1<<<dim3(NBE * 5, I_ / 256), 256, 0, stream>>>(xh, wt, tki, mid);
    // reuse WT region for w2t (stream-ordered after gemm1 finished reading w1t)
    k_transpose<I_, H_><<<dim3(H_ / 64, I_ / 64, E_), 256, 0, stream>>>(w2, wt);
    k_gemm2<<<dim3(NBE * 5, H_ / 256), 256, 0, stream>>>(mid, wt, tki, tkw, out);
    k_final<<<(NTOK * H_ / 4) / 256, 256, 0, stream>>>(out, counts, scal,
                                                       out + (size_t)NTOK * H_);
}